// Round 11
// baseline (74.522 us; speedup 1.0000x reference)
//
#include <hip/hip_runtime.h>

typedef __attribute__((ext_vector_type(8))) short short8;
typedef __attribute__((ext_vector_type(4))) float f32x4;

__device__ __forceinline__ unsigned short f2bf(float f) {
  union { float f; unsigned u; } v; v.f = f;
  unsigned r = v.u + 0x7FFFu + ((v.u >> 16) & 1u);
  return (unsigned short)(r >> 16);
}

__device__ __forceinline__ short8 pack8(f32x4 a, f32x4 b) {
  short8 p;
  p[0] = (short)f2bf(a.x); p[1] = (short)f2bf(a.y);
  p[2] = (short)f2bf(a.z); p[3] = (short)f2bf(a.w);
  p[4] = (short)f2bf(b.x); p[5] = (short)f2bf(b.y);
  p[6] = (short)f2bf(b.z); p[7] = (short)f2bf(b.w);
  return p;
}

// interleave Pe (even ch) / Po (odd ch) back to channel order
__device__ __forceinline__ short8 packEO(f32x4 e, f32x4 o) {
  short8 p;
  p[0] = (short)f2bf(e.x); p[1] = (short)f2bf(o.x);
  p[2] = (short)f2bf(e.y); p[3] = (short)f2bf(o.y);
  p[4] = (short)f2bf(e.z); p[5] = (short)f2bf(o.z);
  p[6] = (short)f2bf(e.w); p[7] = (short)f2bf(o.w);
  return p;
}

// x: (8,64,64,128) f32 ; offset: (8,64,64,18) ; modulation: (8,64,64,9)
// conv_kernel: (3,3,128,256) ; bias: (256,) ; out: (8,64,64,256) f32
// GEMM view: M=32768 (b,oh,ow), K=1152, N=256.
constexpr int KKt = 1152;
constexpr int Ff  = 256;
constexpr size_t WT_BYTES = (size_t)KKt * Ff * 2;            // 589,824
constexpr size_t XB_BYTES = (size_t)8 * 64 * 64 * 128 * 2;   // 8,388,608

// ============ k1: x->bf16 (2048 blocks) | wt transpose (1152 blocks) =======
// wtB fragment-major: idx = ((((ch*4+ks)*16+ft)*4+kg)*16+fr)*8+j holds
// element (f = ft*16+fr, k = ch*128+ks*32+kg*8+j); (ft*4+kg)*16+fr = ft*64+lane.
__global__ __launch_bounds__(256) void prep_small(
    const float* __restrict__ x, const float* __restrict__ kf,
    unsigned short* __restrict__ xb, unsigned short* __restrict__ wtB) {
  const int bid = blockIdx.x;
  if (bid < 2048) {
    int i = (bid * 256 + threadIdx.x) * 8;
    const f32x4* p = (const f32x4*)(x + i);
    *(short8*)(xb + i) = pack8(p[0], p[1]);
  } else {
    int idx = (bid - 2048) * 256 + threadIdx.x;
    int j  = idx & 7;
    int fr = (idx >> 3) & 15;
    int kg = (idx >> 7) & 3;
    int ft = (idx >> 9) & 15;
    int ks = (idx >> 13) & 3;
    int ch = idx >> 15;
    int k = ch * 128 + ks * 32 + kg * 8 + j;
    int f = ft * 16 + fr;
    wtB[idx] = f2bf(kf[k * Ff + f]);
  }
}

// ============ main: 1024 blocks x 512 threads — 4 barrier domains per CU ===
// Block = (b, oh, mseg): 32 output pixels (ow in [mseg*32,+32)) x all 256 F.
// 8 waves: mh = wv&1 -> 16 rows, fq = wv>>1 -> 64 F-cols; acc[4] (16 VGPR).
// A-fragment reuse = 4 MFMA per ds_read. 4 blocks/CU under launch_bounds(512,8)
// -> 32 waves/CU cap with 4 INDEPENDENT barrier groups (the R10 lesson: one
// big barrier-synced block leaves the CU idle at each convergence point).
__global__ __launch_bounds__(512, 8) void dcn_m32(
    const unsigned short* __restrict__ xb, const float* __restrict__ off,
    const float* __restrict__ mo, const unsigned short* __restrict__ wtB,
    const float* __restrict__ bias, float* __restrict__ out) {
  // A tile: 32 rows x 128 ch bf16, row stride 272 B (+16B pad), double buffer.
  __shared__ __align__(16) char At[2][32 * 272];

  const int b    = blockIdx.x & 7;    // one batch image per XCD (xb L2-resident)
  const int q    = blockIdx.x >> 3;
  const int oh   = q >> 1;
  const int mseg = q & 1;             // ow half: [mseg*32, mseg*32+32)
  const int t  = threadIdx.x;
  const int lane = t & 63;
  const int wv   = t >> 6;
  const int mh   = wv & 1;            // rows [mh*16, +16)
  const int fq   = wv >> 1;           // F cols [fq*64, +64)
  const int fr   = lane & 15;
  const int kg   = lane >> 4;
  const int sow  = t >> 4;            // staging row 0..31
  const int c8   = t & 15;            // 8-channel group

  f32x4 acc[4];
#pragma unroll
  for (int i = 0; i < 4; ++i) acc[i] = f32x4{0.f, 0.f, 0.f, 0.f};

  float oyr[2], oxr[2], mmr[2];
  int   og[4]; float wg[4];
  const int ow = mseg * 32 + sow;

  auto loadOff = [&](int ch, int sl) {
    const int dy = ch / 3, dxk = ch - dy * 3;
    const int r = 3 * oh + dy, hp = r & 63, kp = ((r >> 6) * 3) + dxk;
    const int pix = (b * 64 + hp) * 64 + ow;
    oyr[sl] = off[pix * 18 + kp];
    oxr[sl] = off[pix * 18 + 9 + kp];
    mmr[sl] = mo[pix * 9 + kp];
  };
  auto calcW = [&](int ch, int sl) {
    const int dy = ch / 3, dxk = ch - dy * 3;
    const int r = 3 * oh + dy, hp = r & 63, kp = ((r >> 6) * 3) + dxk;
    const float py = oyr[sl] + (float)(hp + kp / 3);
    const float px = oxr[sl] + (float)(ow + kp % 3);
    const float mm = mmr[sl];
    const float y0f = floorf(py), x0f = floorf(px);
    const float y0 = fminf(fmaxf(y0f, 0.f), 65.f);
    const float y1 = fminf(fmaxf(y0f + 1.f, 0.f), 65.f);
    const float x0 = fminf(fmaxf(x0f, 0.f), 65.f);
    const float x1 = fminf(fmaxf(x0f + 1.f, 0.f), 65.f);
    const float ly = fminf(fmaxf(py, 0.f), 65.f) - y0;
    const float lx = fminf(fmaxf(px, 0.f), 65.f) - x0;
    // reference's corner<->weight pairing, matched exactly:
    wg[0] = (1.f - ly) * (1.f - lx) * mm;   // (y0,x0)
    wg[1] = (1.f - ly) * lx * mm;           // (y1,x0)
    wg[2] = ly * (1.f - lx) * mm;           // (y0,x1)
    wg[3] = ly * lx * mm;                   // (y1,x1)
    const int iy0 = (int)y0, iy1 = (int)y1, ix0 = (int)x0, ix1 = (int)x1;
    const int yy[4] = {iy0, iy1, iy0, iy1};
    const int xx[4] = {ix0, ix0, ix1, ix1};
#pragma unroll
    for (int j = 0; j < 4; ++j) {
      const bool v = (yy[j] >= 1) & (yy[j] <= 64) & (xx[j] >= 1) & (xx[j] <= 64);
      int o = ((b * 64 + yy[j] - 1) * 64 + (xx[j] - 1)) * 128 + c8 * 8;
      if (!v) { o = 0; wg[j] = 0.f; }
      og[j] = o;
    }
  };
  auto ldQ = [&](int c) -> short8 { return *(const short8*)(xb + og[c]); };
  auto accQ = [&](short8 s, float w, f32x4& Pe, f32x4& Po) {
    union { short8 s; unsigned u[4]; } v; v.s = s;
#pragma unroll
    for (int i = 0; i < 4; ++i) {
      union { unsigned u; float f; } e, o;
      e.u = v.u[i] << 16;
      o.u = v.u[i] & 0xffff0000u;
      Pe[i] = fmaf(w, e.f, Pe[i]);
      Po[i] = fmaf(w, o.f, Po[i]);
    }
  };
  // one k-step: 1 A-fragment ds_read feeds 4 MFMA (nb = 0..3)
  auto mmah = [&](int buf, int ch, int ks) {
    short8 af = *(const short8*)(At[buf] + (mh * 16 + fr) * 272 + ks * 64 + kg * 16);
    const unsigned short* bp =
        wtB + ((((ch * 4 + ks) * 16 + fq * 4) * 64 + lane) << 3);
#pragma unroll
    for (int nb = 0; nb < 4; ++nb) {
      short8 bf = *(const short8*)(bp + (nb << 9));
      acc[nb] = __builtin_amdgcn_mfma_f32_16x16x32_bf16(af, bf, acc[nb], 0, 0, 0);
    }
  };

  const int wb = sow * 272 + c8 * 16;

  // ---- prologue: stage chunk 0 ----
  loadOff(0, 0); loadOff(1, 1);
  calcW(0, 0);
  {
    short8 q0 = ldQ(0), q1 = ldQ(1), q2 = ldQ(2), q3 = ldQ(3);
    f32x4 Pe{0,0,0,0}, Po{0,0,0,0};
    accQ(q0, wg[0], Pe, Po); accQ(q1, wg[1], Pe, Po);
    accQ(q2, wg[2], Pe, Po); accQ(q3, wg[3], Pe, Po);
    *(short8*)(At[0] + wb) = packEO(Pe, Po);
  }
  __syncthreads();

  // ---- main loop: compute chunk ch, stage chunk ch+1, 1 barrier/chunk ----
#pragma unroll
  for (int ch = 0; ch < 9; ++ch) {
    const int buf = ch & 1;
    const bool hv = ch < 8;
    short8 q0, q1, q2, q3;
    f32x4 Pe{0,0,0,0}, Po{0,0,0,0};
    if (hv) {
      calcW(ch + 1, (ch + 1) & 1);       // offsets were loaded last iteration
      q0 = ldQ(0); q1 = ldQ(1);          // issue corner pair 1
    }
    mmah(buf, ch, 0);
    if (hv) {
      q2 = ldQ(2); q3 = ldQ(3);          // issue corner pair 2
      accQ(q0, wg[0], Pe, Po);
    }
    mmah(buf, ch, 1);
    if (hv) accQ(q1, wg[1], Pe, Po);
    if (ch < 7) loadOff(ch + 2, ch & 1);
    mmah(buf, ch, 2);
    if (hv) {
      accQ(q2, wg[2], Pe, Po);
      accQ(q3, wg[3], Pe, Po);
      *(short8*)(At[buf ^ 1] + wb) = packEO(Pe, Po);
    }
    mmah(buf, ch, 3);
    __syncthreads();
  }

  // ---- epilogue: D layout col(F)=lane&15, row(M)=(lane>>4)*4+reg ----
  float bs[4];
#pragma unroll
  for (int nb = 0; nb < 4; ++nb) bs[nb] = bias[fq * 64 + nb * 16 + fr];
  float* orow = out + ((long)(b * 64 + oh) * 64 + mseg * 32) * 256;
#pragma unroll
  for (int j = 0; j < 4; ++j) {
    const int row = mh * 16 + kg * 4 + j;
#pragma unroll
    for (int nb = 0; nb < 4; ++nb)
      orow[row * 256 + fq * 64 + nb * 16 + fr] = acc[nb][j] + bs[nb];
  }
}

// ============ fallback (ws < WT+XB): R5 f32-gather kernel ==================
__global__ __launch_bounds__(512, 4) void dcn_f32(
    const float* __restrict__ x, const float* __restrict__ off,
    const float* __restrict__ mo, const unsigned short* __restrict__ wtB,
    const float* __restrict__ bias, float* __restrict__ out) {
  __shared__ __align__(16) char At[2][64 * 272];
  const int b  = blockIdx.x & 7;
  const int oh = blockIdx.x >> 3;
  const int t  = threadIdx.x;
  const int lane = t & 63;
  const int wv   = t >> 6;
  const int fr   = lane & 15;
  const int kg   = lane >> 4;
  const int sow  = t >> 3;
  const int c16  = t & 7;

  f32x4 acc[4][2];
#pragma unroll
  for (int i = 0; i < 4; ++i) { acc[i][0] = f32x4{0,0,0,0}; acc[i][1] = f32x4{0,0,0,0}; }
  float oyr[2], oxr[2], mmr[2];
  int   og[4]; float wg[4];

  auto loadOff = [&](int ch, int sl) {
    const int dy = ch / 3, dxk = ch - dy * 3;
    const int r = 3 * oh + dy, hp = r & 63, kp = ((r >> 6) * 3) + dxk;
    const int pix = (b * 64 + hp) * 64 + sow;
    oyr[sl] = off[pix * 18 + kp];
    oxr[sl] = off[pix * 18 + 9 + kp];
    mmr[sl] = mo[pix * 9 + kp];
  };
  auto calcW = [&](int ch, int sl) {
    const int dy = ch / 3, dxk = ch - dy * 3;
    const int r = 3 * oh + dy, hp = r & 63, kp = ((r >> 6) * 3) + dxk;
    const float py = oyr[sl] + (float)(hp + kp / 3);
    const float px = oxr[sl] + (float)(sow + kp % 3);
    const float mm = mmr[sl];
    const float y0f = floorf(py), x0f = floorf(px);
    const float y0 = fminf(fmaxf(y0f, 0.f), 65.f);
    const float y1 = fminf(fmaxf(y0f + 1.f, 0.f), 65.f);
    const float x0 = fminf(fmaxf(x0f, 0.f), 65.f);
    const float x1 = fminf(fmaxf(x0f + 1.f, 0.f), 65.f);
    const float ly = fminf(fmaxf(py, 0.f), 65.f) - y0;
    const float lx = fminf(fmaxf(px, 0.f), 65.f) - x0;
    wg[0] = (1.f - ly) * (1.f - lx) * mm;
    wg[1] = (1.f - ly) * lx * mm;
    wg[2] = ly * (1.f - lx) * mm;
    wg[3] = ly * lx * mm;
    const int iy0 = (int)y0, iy1 = (int)y1, ix0 = (int)x0, ix1 = (int)x1;
    const int yy[4] = {iy0, iy1, iy0, iy1};
    const int xx[4] = {ix0, ix0, ix1, ix1};
#pragma unroll
    for (int j = 0; j < 4; ++j) {
      const bool v = (yy[j] >= 1) & (yy[j] <= 64) & (xx[j] >= 1) & (xx[j] <= 64);
      int o = ((b * 64 + yy[j] - 1) * 64 + (xx[j] - 1)) * 128 + c16 * 16;
      if (!v) { o = 0; wg[j] = 0.f; }
      og[j] = o;
    }
  };
  auto ldB = [&](int ch, int ks, short8* bf) {
    const unsigned short* p = wtB + (((ch * 4 + ks) * 16 + wv * 2) * 64 + lane) * 8;
    bf[0] = *(const short8*)p;
    bf[1] = *(const short8*)(p + 512);
  };
  auto mmah = [&](int buf, int ks, const short8* bf) {
    short8 af[4];
#pragma unroll
    for (int m2 = 0; m2 < 4; ++m2)
      af[m2] = *(const short8*)(At[buf] + (m2 * 16 + fr) * 272 + ks * 64 + kg * 16);
#pragma unroll
    for (int m2 = 0; m2 < 4; ++m2)
#pragma unroll
      for (int nb = 0; nb < 2; ++nb)
        acc[m2][nb] = __builtin_amdgcn_mfma_f32_16x16x32_bf16(af[m2], bf[nb], acc[m2][nb], 0, 0, 0);
  };
  auto ldC = [&](int c, f32x4* G) {
    const f32x4* p = (const f32x4*)(x + og[c]);
    G[0] = p[0]; G[1] = p[1]; G[2] = p[2]; G[3] = p[3];
  };
  const int wb = sow * 272 + c16 * 32;
  loadOff(0, 0); loadOff(1, 1);
  calcW(0, 0);
  {
    f32x4 G0[4], G1[4];
    ldC(0, G0); ldC(1, G1);
    f32x4 P0 = wg[0]*G0[0] + wg[1]*G1[0], P1 = wg[0]*G0[1] + wg[1]*G1[1];
    f32x4 P2 = wg[0]*G0[2] + wg[1]*G1[2], P3 = wg[0]*G0[3] + wg[1]*G1[3];
    ldC(2, G0); ldC(3, G1);
    P0 += wg[2]*G0[0] + wg[3]*G1[0]; P1 += wg[2]*G0[1] + wg[3]*G1[1];
    P2 += wg[2]*G0[2] + wg[3]*G1[2]; P3 += wg[2]*G0[3] + wg[3]*G1[3];
    *(short8*)(At[0] + wb)      = pack8(P0, P1);
    *(short8*)(At[0] + wb + 16) = pack8(P2, P3);
  }
  __syncthreads();
#pragma unroll
  for (int ch = 0; ch < 9; ++ch) {
    const int buf = ch & 1;
    const bool hv = ch < 8;
    if (hv) calcW(ch + 1, (ch + 1) & 1);
    short8 bA[2], bB[2];
    f32x4 G0[4], G1[4], P0, P1, P2, P3;
    ldB(ch, 0, bA);
    if (hv) ldC(0, G0);
    ldB(ch, 1, bB);
    mmah(buf, 0, bA);
    if (hv) { P0 = wg[0]*G0[0]; P1 = wg[0]*G0[1]; P2 = wg[0]*G0[2]; P3 = wg[0]*G0[3]; }
    if (hv) ldC(1, G1);
    ldB(ch, 2, bA);
    mmah(buf, 1, bB);
    if (hv) { P0 += wg[1]*G1[0]; P1 += wg[1]*G1[1]; P2 += wg[1]*G1[2]; P3 += wg[1]*G1[3]; }
    if (hv) ldC(2, G0);
    ldB(ch, 3, bB);
    if (ch < 7) loadOff(ch + 2, ch & 1);
    mmah(buf, 2, bA);
    if (hv) { P0 += wg[2]*G0[0]; P1 += wg[2]*G0[1]; P2 += wg[2]*G0[2]; P3 += wg[2]*G0[3]; }
    if (hv) ldC(3, G1);
    mmah(buf, 3, bB);
    if (hv) {
      P0 += wg[3]*G1[0]; P1 += wg[3]*G1[1]; P2 += wg[3]*G1[2]; P3 += wg[3]*G1[3];
      *(short8*)(At[buf ^ 1] + wb)      = pack8(P0, P1);
      *(short8*)(At[buf ^ 1] + wb + 16) = pack8(P2, P3);
    }
    __syncthreads();
  }
  float bs[2];
#pragma unroll
  for (int nb = 0; nb < 2; ++nb) bs[nb] = bias[wv * 32 + nb * 16 + fr];
  float* orow = out + (long)(b * 64 + oh) * 64 * 256;
#pragma unroll
  for (int m2 = 0; m2 < 4; ++m2) {
#pragma unroll
    for (int j = 0; j < 4; ++j) {
      const int ow = m2 * 16 + kg * 4 + j;
#pragma unroll
      for (int nb = 0; nb < 2; ++nb)
        orow[ow * 256 + wv * 32 + nb * 16 + fr] = acc[m2][nb][j] + bs[nb];
    }
  }
}

__global__ void wt_prep_only(const float* __restrict__ kf, unsigned short* __restrict__ wtB) {
  int idx = blockIdx.x * 256 + threadIdx.x;
  int j  = idx & 7;
  int fr = (idx >> 3) & 15;
  int kg = (idx >> 7) & 3;
  int ft = (idx >> 9) & 15;
  int ks = (idx >> 13) & 3;
  int ch = idx >> 15;
  int k = ch * 128 + ks * 32 + kg * 8 + j;
  int f = ft * 16 + fr;
  wtB[idx] = f2bf(kf[k * Ff + f]);
}

extern "C" void kernel_launch(void* const* d_in, const int* in_sizes, int n_in,
                              void* d_out, int out_size, void* d_ws, size_t ws_size,
                              hipStream_t stream) {
  const float* x    = (const float*)d_in[0];
  const float* off  = (const float*)d_in[1];
  const float* mo   = (const float*)d_in[2];
  const float* kf   = (const float*)d_in[3];
  const float* bias = (const float*)d_in[4];
  float* outp = (float*)d_out;
  unsigned short* wtB = (unsigned short*)d_ws;

  if (ws_size >= WT_BYTES + XB_BYTES) {
    unsigned short* xb = (unsigned short*)((char*)d_ws + WT_BYTES);
    prep_small<<<3200, 256, 0, stream>>>(x, kf, xb, wtB);
    dcn_m32<<<1024, 512, 0, stream>>>(xb, off, mo, wtB, bias, outp);
  } else {
    wt_prep_only<<<1152, 256, 0, stream>>>(kf, wtB);
    dcn_f32<<<512, 512, 0, stream>>>(x, off, mo, wtB, bias, outp);
  }
}

// Round 14
// 52.899 us; speedup vs baseline: 1.4088x; 1.4088x over previous
//
#include <hip/hip_runtime.h>

typedef __attribute__((ext_vector_type(8))) short short8;
typedef __attribute__((ext_vector_type(4))) float f32x4;

__device__ __forceinline__ unsigned short f2bf(float f) {
  union { float f; unsigned u; } v; v.f = f;
  unsigned r = v.u + 0x7FFFu + ((v.u >> 16) & 1u);
  return (unsigned short)(r >> 16);
}

__device__ __forceinline__ short8 pack8(f32x4 a, f32x4 b) {
  short8 p;
  p[0] = (short)f2bf(a.x); p[1] = (short)f2bf(a.y);
  p[2] = (short)f2bf(a.z); p[3] = (short)f2bf(a.w);
  p[4] = (short)f2bf(b.x); p[5] = (short)f2bf(b.y);
  p[6] = (short)f2bf(b.z); p[7] = (short)f2bf(b.w);
  return p;
}

// interleave Pe (even ch) / Po (odd ch) back to channel order
__device__ __forceinline__ short8 packEO(f32x4 e, f32x4 o) {
  short8 p;
  p[0] = (short)f2bf(e.x); p[1] = (short)f2bf(o.x);
  p[2] = (short)f2bf(e.y); p[3] = (short)f2bf(o.y);
  p[4] = (short)f2bf(e.z); p[5] = (short)f2bf(o.z);
  p[6] = (short)f2bf(e.w); p[7] = (short)f2bf(o.w);
  return p;
}

// x: (8,64,64,128) f32 ; offset: (8,64,64,18) ; modulation: (8,64,64,9)
// conv_kernel: (3,3,128,256) ; bias: (256,) ; out: (8,64,64,256) f32
// GEMM view: M=32768 (b,oh,ow), K=1152, N=256.
constexpr int KKt = 1152;
constexpr int Ff  = 256;
constexpr size_t WT_BYTES = (size_t)KKt * Ff * 2;            // 589,824
constexpr size_t XB_BYTES = (size_t)8 * 64 * 64 * 128 * 2;   // 8,388,608

// ============ k1: x->bf16 (2048 blocks) | wt transpose (1152 blocks) =======
// wtB fragment-major: idx = ((((ch*4+ks)*16+ft)*4+kg)*16+fr)*8+j holds
// element (f = ft*16+fr, k = ch*128+ks*32+kg*8+j).  [proven R9]
__global__ __launch_bounds__(256) void prep_small(
    const float* __restrict__ x, const float* __restrict__ kf,
    unsigned short* __restrict__ xb, unsigned short* __restrict__ wtB) {
  const int bid = blockIdx.x;
  if (bid < 2048) {
    int i = (bid * 256 + threadIdx.x) * 8;
    const f32x4* p = (const f32x4*)(x + i);
    *(short8*)(xb + i) = pack8(p[0], p[1]);
  } else {
    int idx = (bid - 2048) * 256 + threadIdx.x;
    int j  = idx & 7;
    int fr = (idx >> 3) & 15;
    int kg = (idx >> 7) & 3;
    int ft = (idx >> 9) & 15;
    int ks = (idx >> 13) & 3;
    int ch = idx >> 15;
    int k = ch * 128 + ks * 32 + kg * 8 + j;
    int f = ft * 16 + fr;
    wtB[idx] = f2bf(kf[k * Ff + f]);
  }
}

// ============ main: fused gather+GEMM, 512 blocks x 1024 threads ===========
// [proven R7: 46 us main, absmax 0.0078]
// Waves = 2x8 grid: mh = wv&1 (32 M-rows), fq = wv>>1 (32 F-cols). 2 blk/CU.
__global__ __launch_bounds__(1024, 8) void dcn_bf16(
    const unsigned short* __restrict__ xb, const float* __restrict__ off,
    const float* __restrict__ mo, const unsigned short* __restrict__ wtB,
    const float* __restrict__ bias, float* __restrict__ out) {
  // A tile, row stride 272 B (+16B pad): uniform bank spread on write & read.
  __shared__ __align__(16) char At[2][64 * 272];

  const int b  = blockIdx.x & 7;      // one batch image per XCD (xb L2-resident)
  const int oh = blockIdx.x >> 3;
  const int t  = threadIdx.x;
  const int lane = t & 63;
  const int wv   = t >> 6;
  const int mh   = wv & 1;
  const int fq   = wv >> 1;
  const int fr   = lane & 15;
  const int kg   = lane >> 4;
  const int sow  = t >> 4;            // staging: 16 threads per row
  const int c8   = t & 15;            // 8-channel group

  f32x4 acc[2][2];
#pragma unroll
  for (int i = 0; i < 2; ++i) { acc[i][0] = f32x4{0,0,0,0}; acc[i][1] = f32x4{0,0,0,0}; }
  float oyr[2], oxr[2], mmr[2];
  int   og[4]; float wg[4];

  auto loadOff = [&](int ch, int sl) {
    const int dy = ch / 3, dxk = ch - dy * 3;
    const int r = 3 * oh + dy, hp = r & 63, kp = ((r >> 6) * 3) + dxk;
    const int pix = (b * 64 + hp) * 64 + sow;
    oyr[sl] = off[pix * 18 + kp];
    oxr[sl] = off[pix * 18 + 9 + kp];
    mmr[sl] = mo[pix * 9 + kp];
  };
  auto calcW = [&](int ch, int sl) {
    const int dy = ch / 3, dxk = ch - dy * 3;
    const int r = 3 * oh + dy, hp = r & 63, kp = ((r >> 6) * 3) + dxk;
    const float py = oyr[sl] + (float)(hp + kp / 3);
    const float px = oxr[sl] + (float)(sow + kp % 3);
    const float mm = mmr[sl];
    const float y0f = floorf(py), x0f = floorf(px);
    const float y0 = fminf(fmaxf(y0f, 0.f), 65.f);
    const float y1 = fminf(fmaxf(y0f + 1.f, 0.f), 65.f);
    const float x0 = fminf(fmaxf(x0f, 0.f), 65.f);
    const float x1 = fminf(fmaxf(x0f + 1.f, 0.f), 65.f);
    const float ly = fminf(fmaxf(py, 0.f), 65.f) - y0;
    const float lx = fminf(fmaxf(px, 0.f), 65.f) - x0;
    // reference's corner<->weight pairing, matched exactly:
    wg[0] = (1.f - ly) * (1.f - lx) * mm;   // (y0,x0)
    wg[1] = (1.f - ly) * lx * mm;           // (y1,x0)
    wg[2] = ly * (1.f - lx) * mm;           // (y0,x1)
    wg[3] = ly * lx * mm;                   // (y1,x1)
    const int iy0 = (int)y0, iy1 = (int)y1, ix0 = (int)x0, ix1 = (int)x1;
    const int yy[4] = {iy0, iy1, iy0, iy1};
    const int xx[4] = {ix0, ix0, ix1, ix1};
#pragma unroll
    for (int j = 0; j < 4; ++j) {
      const bool v = (yy[j] >= 1) & (yy[j] <= 64) & (xx[j] >= 1) & (xx[j] <= 64);
      int o = ((b * 64 + yy[j] - 1) * 64 + (xx[j] - 1)) * 128 + c8 * 8;
      if (!v) { o = 0; wg[j] = 0.f; }
      og[j] = o;
    }
  };
  auto ldQ = [&](int c) -> short8 { return *(const short8*)(xb + og[c]); };
  auto accQ = [&](short8 s, float w, f32x4& Pe, f32x4& Po) {
    union { short8 s; unsigned u[4]; } v; v.s = s;
#pragma unroll
    for (int i = 0; i < 4; ++i) {
      union { unsigned u; float f; } e, o;
      e.u = v.u[i] << 16;
      o.u = v.u[i] & 0xffff0000u;
      Pe[i] = fmaf(w, e.f, Pe[i]);
      Po[i] = fmaf(w, o.f, Po[i]);
    }
  };
  auto mmah = [&](int buf, int ch, int ks) {
    const unsigned short* bp = wtB + (((ch * 4 + ks) * 16 + fq * 2) * 64 + lane) * 8;
    short8 bf0 = *(const short8*)bp;
    short8 bf1 = *(const short8*)(bp + 512);
    short8 af[2];
#pragma unroll
    for (int m2 = 0; m2 < 2; ++m2)
      af[m2] = *(const short8*)(At[buf] + (mh * 32 + m2 * 16 + fr) * 272 + ks * 64 + kg * 16);
#pragma unroll
    for (int m2 = 0; m2 < 2; ++m2) {
      acc[m2][0] = __builtin_amdgcn_mfma_f32_16x16x32_bf16(af[m2], bf0, acc[m2][0], 0, 0, 0);
      acc[m2][1] = __builtin_amdgcn_mfma_f32_16x16x32_bf16(af[m2], bf1, acc[m2][1], 0, 0, 0);
    }
  };
  const int wb = sow * 272 + c8 * 16;

  // ---- prologue: stage chunk 0 ----
  loadOff(0, 0); loadOff(1, 1);
  calcW(0, 0);
  {
    short8 q0 = ldQ(0), q1 = ldQ(1), q2 = ldQ(2), q3 = ldQ(3);
    f32x4 Pe{0,0,0,0}, Po{0,0,0,0};
    accQ(q0, wg[0], Pe, Po); accQ(q1, wg[1], Pe, Po);
    accQ(q2, wg[2], Pe, Po); accQ(q3, wg[3], Pe, Po);
    *(short8*)(At[0] + wb) = packEO(Pe, Po);
  }
  __syncthreads();

  // ---- main loop: compute chunk ch, stage chunk ch+1, 1 barrier/chunk ----
#pragma unroll
  for (int ch = 0; ch < 9; ++ch) {
    const int buf = ch & 1;
    const bool hv = ch < 8;
    short8 q0, q1, q2, q3;
    f32x4 Pe{0,0,0,0}, Po{0,0,0,0};
    if (hv) {
      calcW(ch + 1, (ch + 1) & 1);       // offsets were loaded last iteration
      q0 = ldQ(0); q1 = ldQ(1);          // issue corner pair 1
    }
    mmah(buf, ch, 0);
    if (hv) {
      q2 = ldQ(2); q3 = ldQ(3);          // issue corner pair 2
      accQ(q0, wg[0], Pe, Po);
    }
    mmah(buf, ch, 1);
    if (hv) accQ(q1, wg[1], Pe, Po);
    if (ch < 7) loadOff(ch + 2, ch & 1);
    mmah(buf, ch, 2);
    if (hv) {
      accQ(q2, wg[2], Pe, Po);
      accQ(q3, wg[3], Pe, Po);
      *(short8*)(At[buf ^ 1] + wb) = packEO(Pe, Po);
    }
    mmah(buf, ch, 3);
    __syncthreads();
  }

  // ---- epilogue: D layout col(F)=lane&15, row(M)=(lane>>4)*4+reg ----
  float bs[2];
#pragma unroll
  for (int nb = 0; nb < 2; ++nb) bs[nb] = bias[fq * 32 + nb * 16 + fr];
  float* orow = out + (long)(b * 64 + oh) * 64 * 256;
#pragma unroll
  for (int m2 = 0; m2 < 2; ++m2) {
#pragma unroll
    for (int j = 0; j < 4; ++j) {
      const int row = mh * 32 + m2 * 16 + kg * 4 + j;
#pragma unroll
      for (int nb = 0; nb < 2; ++nb)
        orow[row * 256 + fq * 32 + nb * 16 + fr] = acc[m2][nb][j] + bs[nb];
    }
  }
}

// ============ fallback (ws < WT+XB): R5 f32-gather kernel ==================
__global__ __launch_bounds__(512, 4) void dcn_f32(
    const float* __restrict__ x, const float* __restrict__ off,
    const float* __restrict__ mo, const unsigned short* __restrict__ wtB,
    const float* __restrict__ bias, float* __restrict__ out) {
  __shared__ __align__(16) char At[2][64 * 272];
  const int b  = blockIdx.x & 7;
  const int oh = blockIdx.x >> 3;
  const int t  = threadIdx.x;
  const int lane = t & 63;
  const int wv   = t >> 6;
  const int fr   = lane & 15;
  const int kg   = lane >> 4;
  const int sow  = t >> 3;
  const int c16  = t & 7;

  f32x4 acc[4][2];
#pragma unroll
  for (int i = 0; i < 4; ++i) { acc[i][0] = f32x4{0,0,0,0}; acc[i][1] = f32x4{0,0,0,0}; }
  float oyr[2], oxr[2], mmr[2];
  int   og[4]; float wg[4];

  auto loadOff = [&](int ch, int sl) {
    const int dy = ch / 3, dxk = ch - dy * 3;
    const int r = 3 * oh + dy, hp = r & 63, kp = ((r >> 6) * 3) + dxk;
    const int pix = (b * 64 + hp) * 64 + sow;
    oyr[sl] = off[pix * 18 + kp];
    oxr[sl] = off[pix * 18 + 9 + kp];
    mmr[sl] = mo[pix * 9 + kp];
  };
  auto calcW = [&](int ch, int sl) {
    const int dy = ch / 3, dxk = ch - dy * 3;
    const int r = 3 * oh + dy, hp = r & 63, kp = ((r >> 6) * 3) + dxk;
    const float py = oyr[sl] + (float)(hp + kp / 3);
    const float px = oxr[sl] + (float)(sow + kp % 3);
    const float mm = mmr[sl];
    const float y0f = floorf(py), x0f = floorf(px);
    const float y0 = fminf(fmaxf(y0f, 0.f), 65.f);
    const float y1 = fminf(fmaxf(y0f + 1.f, 0.f), 65.f);
    const float x0 = fminf(fmaxf(x0f, 0.f), 65.f);
    const float x1 = fminf(fmaxf(x0f + 1.f, 0.f), 65.f);
    const float ly = fminf(fmaxf(py, 0.f), 65.f) - y0;
    const float lx = fminf(fmaxf(px, 0.f), 65.f) - x0;
    wg[0] = (1.f - ly) * (1.f - lx) * mm;
    wg[1] = (1.f - ly) * lx * mm;
    wg[2] = ly * (1.f - lx) * mm;
    wg[3] = ly * lx * mm;
    const int iy0 = (int)y0, iy1 = (int)y1, ix0 = (int)x0, ix1 = (int)x1;
    const int yy[4] = {iy0, iy1, iy0, iy1};
    const int xx[4] = {ix0, ix0, ix1, ix1};
#pragma unroll
    for (int j = 0; j < 4; ++j) {
      const bool v = (yy[j] >= 1) & (yy[j] <= 64) & (xx[j] >= 1) & (xx[j] <= 64);
      int o = ((b * 64 + yy[j] - 1) * 64 + (xx[j] - 1)) * 128 + c16 * 16;
      if (!v) { o = 0; wg[j] = 0.f; }
      og[j] = o;
    }
  };
  auto ldB = [&](int ch, int ks, short8* bf) {
    const unsigned short* p = wtB + (((ch * 4 + ks) * 16 + wv * 2) * 64 + lane) * 8;
    bf[0] = *(const short8*)p;
    bf[1] = *(const short8*)(p + 512);
  };
  auto mmah = [&](int buf, int ks, const short8* bf) {
    short8 af[4];
#pragma unroll
    for (int m2 = 0; m2 < 4; ++m2)
      af[m2] = *(const short8*)(At[buf] + (m2 * 16 + fr) * 272 + ks * 64 + kg * 16);
#pragma unroll
    for (int m2 = 0; m2 < 4; ++m2)
#pragma unroll
      for (int nb = 0; nb < 2; ++nb)
        acc[m2][nb] = __builtin_amdgcn_mfma_f32_16x16x32_bf16(af[m2], bf[nb], acc[m2][nb], 0, 0, 0);
  };
  auto ldC = [&](int c, f32x4* G) {
    const f32x4* p = (const f32x4*)(x + og[c]);
    G[0] = p[0]; G[1] = p[1]; G[2] = p[2]; G[3] = p[3];
  };
  const int wb = sow * 272 + c16 * 32;
  loadOff(0, 0); loadOff(1, 1);
  calcW(0, 0);
  {
    f32x4 G0[4], G1[4];
    ldC(0, G0); ldC(1, G1);
    f32x4 P0 = wg[0]*G0[0] + wg[1]*G1[0], P1 = wg[0]*G0[1] + wg[1]*G1[1];
    f32x4 P2 = wg[0]*G0[2] + wg[1]*G1[2], P3 = wg[0]*G0[3] + wg[1]*G1[3];
    ldC(2, G0); ldC(3, G1);
    P0 += wg[2]*G0[0] + wg[3]*G1[0]; P1 += wg[2]*G0[1] + wg[3]*G1[1];
    P2 += wg[2]*G0[2] + wg[3]*G1[2]; P3 += wg[2]*G0[3] + wg[3]*G1[3];
    *(short8*)(At[0] + wb)      = pack8(P0, P1);
    *(short8*)(At[0] + wb + 16) = pack8(P2, P3);
  }
  __syncthreads();
#pragma unroll
  for (int ch = 0; ch < 9; ++ch) {
    const int buf = ch & 1;
    const bool hv = ch < 8;
    if (hv) calcW(ch + 1, (ch + 1) & 1);
    short8 bA[2], bB[2];
    f32x4 G0[4], G1[4], P0, P1, P2, P3;
    ldB(ch, 0, bA);
    if (hv) ldC(0, G0);
    ldB(ch, 1, bB);
    mmah(buf, 0, bA);
    if (hv) { P0 = wg[0]*G0[0]; P1 = wg[0]*G0[1]; P2 = wg[0]*G0[2]; P3 = wg[0]*G0[3]; }
    if (hv) ldC(1, G1);
    ldB(ch, 2, bA);
    mmah(buf, 1, bB);
    if (hv) { P0 += wg[1]*G1[0]; P1 += wg[1]*G1[1]; P2 += wg[1]*G1[2]; P3 += wg[1]*G1[3]; }
    if (hv) ldC(2, G0);
    ldB(ch, 3, bB);
    if (ch < 7) loadOff(ch + 2, ch & 1);
    mmah(buf, 2, bA);
    if (hv) { P0 += wg[2]*G0[0]; P1 += wg[2]*G0[1]; P2 += wg[2]*G0[2]; P3 += wg[2]*G0[3]; }
    if (hv) ldC(3, G1);
    mmah(buf, 3, bB);
    if (hv) {
      P0 += wg[3]*G1[0]; P1 += wg[3]*G1[1]; P2 += wg[3]*G1[2]; P3 += wg[3]*G1[3];
      *(short8*)(At[buf ^ 1] + wb)      = pack8(P0, P1);
      *(short8*)(At[buf ^ 1] + wb + 16) = pack8(P2, P3);
    }
    __syncthreads();
  }
  float bs[2];
#pragma unroll
  for (int nb = 0; nb < 2; ++nb) bs[nb] = bias[wv * 32 + nb * 16 + fr];
  float* orow = out + (long)(b * 64 + oh) * 64 * 256;
#pragma unroll
  for (int m2 = 0; m2 < 4; ++m2) {
#pragma unroll
    for (int j = 0; j < 4; ++j) {
      const int ow = m2 * 16 + kg * 4 + j;
#pragma unroll
      for (int nb = 0; nb < 2; ++nb)
        orow[ow * 256 + wv * 32 + nb * 16 + fr] = acc[m2][nb][j] + bs[nb];
    }
  }
}

__global__ void wt_prep_only(const float* __restrict__ kf, unsigned short* __restrict__ wtB) {
  int idx = blockIdx.x * 256 + threadIdx.x;
  int j  = idx & 7;
  int fr = (idx >> 3) & 15;
  int kg = (idx >> 7) & 3;
  int ft = (idx >> 9) & 15;
  int ks = (idx >> 13) & 3;
  int ch = idx >> 15;
  int k = ch * 128 + ks * 32 + kg * 8 + j;
  int f = ft * 16 + fr;
  wtB[idx] = f2bf(kf[k * Ff + f]);
}

extern "C" void kernel_launch(void* const* d_in, const int* in_sizes, int n_in,
                              void* d_out, int out_size, void* d_ws, size_t ws_size,
                              hipStream_t stream) {
  const float* x    = (const float*)d_in[0];
  const float* off  = (const float*)d_in[1];
  const float* mo   = (const float*)d_in[2];
  const float* kf   = (const float*)d_in[3];
  const float* bias = (const float*)d_in[4];
  float* outp = (float*)d_out;
  unsigned short* wtB = (unsigned short*)d_ws;

  if (ws_size >= WT_BYTES + XB_BYTES) {
    unsigned short* xb = (unsigned short*)((char*)d_ws + WT_BYTES);
    prep_small<<<3200, 256, 0, stream>>>(x, kf, xb, wtB);
    dcn_bf16<<<512, 1024, 0, stream>>>(xb, off, mo, wtB, bias, outp);
  } else {
    wt_prep_only<<<1152, 256, 0, stream>>>(kf, wtB);
    dcn_f32<<<512, 512, 0, stream>>>(x, off, mo, wtB, bias, outp);
  }
}